// Round 9
// baseline (2918.607 us; speedup 1.0000x reference)
//
#include <hip/hip_runtime.h>
#include <hip/hip_bf16.h>

#define N_NODES 100000
#define N_EDGES 1600000
#define BN_EPS 1e-5f
#define SCAN_BLOCKS 391   // ceil(100000/256)

typedef __hip_bfloat16 bf16;
typedef unsigned long long ull;
typedef float v2f __attribute__((ext_vector_type(2)));

__device__ __forceinline__ float b2f(bf16 v) { return __bfloat162float(v); }
__device__ __forceinline__ float frcp(float x) { return __builtin_amdgcn_rcpf(x); }
__device__ __forceinline__ float fsig(float x) { return frcp(1.0f + __expf(-x)); }
__device__ __forceinline__ float ftanh(float x) {
    return 1.0f - 2.0f * frcp(__expf(2.0f * x) + 1.0f);
}
__device__ __forceinline__ float bfr(uint u) { return __uint_as_float(u << 16); }
__device__ __forceinline__ v2f up(uint u) {
    return (v2f){__uint_as_float(u << 16), __uint_as_float(u & 0xffff0000u)};
}
__device__ __forceinline__ v2f vfma(v2f a, v2f b, v2f c) {
    return __builtin_elementwise_fma(a, b, c);
}
__device__ __forceinline__ uint pk2(const float* p) {
    bf16 a = __float2bfloat16(p[0]), b = __float2bfloat16(p[1]);
    return (uint)*(ushort*)&a | ((uint)*(ushort*)&b << 16);
}

// ---- utility ---------------------------------------------------------------
__global__ void k_zero_f(float* __restrict__ p, int n) {
    int i = blockIdx.x * 256 + threadIdx.x;
    if (i < n) p[i] = 0.f;
}
__global__ void k_marker(float* __restrict__ p, int n, float v) {
    int i = blockIdx.x * 256 + threadIdx.x;
    if (i < n) p[i] = v;
}

// ---- packed histogram: pk[d] += (1<<48)|fx(ew); rank = old count -----------
__global__ void k_hist(const int* __restrict__ ei, const float* __restrict__ ew,
                       ull* __restrict__ pk, int* __restrict__ rank) {
    int e = blockIdx.x * 256 + threadIdx.x;
    if (e < N_EDGES) {
        int d = ei[N_EDGES + e];
        ull v = (1ull << 48) | (ull)((double)ew[e] * 4294967296.0);
        ull old = atomicAdd(&pk[d], v);
        rank[e] = (int)(old >> 48);
    }
}

// ---- parallel scan, stage 1: per-block sums of counts ----------------------
__global__ void k_bsum(const ull* __restrict__ pk, int* __restrict__ bsum) {
    __shared__ int s[256];
    int idx = blockIdx.x * 256 + threadIdx.x;
    s[threadIdx.x] = (idx < N_NODES) ? (int)(pk[idx] >> 48) : 0;
    __syncthreads();
    for (int st = 128; st >= 1; st >>= 1) {
        if (threadIdx.x < st) s[threadIdx.x] += s[threadIdx.x + st];
        __syncthreads();
    }
    if (threadIdx.x == 0) bsum[blockIdx.x] = s[0];
}

// ---- stage 2: exclusive scan of 391 block sums (single tiny block) ---------
__global__ __launch_bounds__(512) void k_bscan(const int* __restrict__ bsum,
                                               int* __restrict__ bbase) {
    __shared__ int s[512];
    int t = threadIdx.x;
    int v = (t < SCAN_BLOCKS) ? bsum[t] : 0;
    s[t] = v; __syncthreads();
    for (int st = 1; st < 512; st <<= 1) {
        int u = (t >= st) ? s[t - st] : 0;
        __syncthreads();
        s[t] += u;
        __syncthreads();
    }
    if (t < SCAN_BLOCKS) bbase[t] = s[t] - v;   // exclusive prefix
}

// ---- stage 3: block scan -> off; unpack deg from pk ------------------------
__global__ void k_scan3(const ull* __restrict__ pk, const int* __restrict__ bbase,
                        int* __restrict__ off, float* __restrict__ deg) {
    __shared__ int wsum[4];
    int idx = blockIdx.x * 256 + threadIdx.x;
    int lane = threadIdx.x & 63, w = threadIdx.x >> 6;
    ull pv = (idx < N_NODES) ? pk[idx] : 0ull;
    int c = (int)(pv >> 48);
    int s = c;
    for (int d = 1; d < 64; d <<= 1) {
        int u = __shfl_up(s, d, 64);
        if (lane >= d) s += u;
    }
    if (lane == 63) wsum[w] = s;
    __syncthreads();
    int wb = 0;
    for (int i = 0; i < w; i++) wb += wsum[i];
    int e = bbase[blockIdx.x] + wb + s - c;      // exclusive
    if (idx < N_NODES) {
        off[idx] = e;
        deg[idx] = (float)((double)(pv & 0xFFFFFFFFFFFFull) * (1.0 / 4294967296.0));
    }
    if (idx == 0) off[N_NODES] = N_EDGES;        // all dst are in-range
}

// ---- scatter edges into CSR slots as {src, norm} — NO atomics --------------
__global__ void k_scatter(const int* __restrict__ ei, const float* __restrict__ ew,
                          const float* __restrict__ deg, const int* __restrict__ off,
                          const int* __restrict__ rank, int2* __restrict__ epk) {
    int e = blockIdx.x * 256 + threadIdx.x;
    if (e < N_EDGES) {
        int s = ei[e], d = ei[N_EDGES + e];
        float nm = ew[e] * rsqrtf((deg[s] + 1.0f) * (deg[d] + 1.0f));
        epk[off[d] + rank[e]] = make_int2(s, __float_as_int(nm));
    }
}

// ---- column sums of x (for skip_avg) ---------------------------------------
__global__ void k_xmean(const float* __restrict__ x, float* __restrict__ xsum) {
    __shared__ float s[256];
    int f = threadIdx.x & 31, rg = threadIdx.x >> 5;
    float acc = 0.f;
    for (int n = blockIdx.x * 8 + rg; n < N_NODES; n += gridDim.x * 8)
        acc += x[n * 32 + f];
    s[threadIdx.x] = acc; __syncthreads();
    for (int st = 128; st >= 32; st >>= 1) {
        if (threadIdx.x < st) s[threadIdx.x] += s[threadIdx.x + st];
        __syncthreads();
    }
    if (threadIdx.x < 32) atomicAdd(&xsum[threadIdx.x], s[threadIdx.x]);
}

// ---- A = x @ W1 (fp32 in, bf16 out) ----------------------------------------
__global__ void k_xw1(const float* __restrict__ x, const float* __restrict__ w,
                      bf16* __restrict__ A) {
    __shared__ float Ws[32 * 33];
    __shared__ float xs[256];
    for (int i = threadIdx.x; i < 1024; i += 256)
        Ws[(i >> 5) * 33 + (i & 31)] = w[i];
    long base = (long)blockIdx.x * 256;
    xs[threadIdx.x] = x[base + threadIdx.x];
    __syncthreads();
    int r = threadIdx.x >> 5, h = threadIdx.x & 31;
    float acc = 0.f;
#pragma unroll
    for (int f = 0; f < 32; f++) acc += xs[r * 32 + f] * Ws[f * 33 + h];
    A[base + threadIdx.x] = __float2bfloat16(acc);
}

// ---- pull-mode GCN: agg + self-loop + bias + relu + BN stats ---------------
__global__ __launch_bounds__(256) void k_gcn(
    const int* __restrict__ off, const int2* __restrict__ epk,
    const bf16* __restrict__ A, const float* __restrict__ deg,
    const float* __restrict__ bias, bf16* __restrict__ B,
    float* __restrict__ sum, float* __restrict__ sq) {
    __shared__ float s1[256], s2[256];
    const ushort* Au = (const ushort*)A;
    int tid = threadIdx.x, f = tid & 31, g = tid >> 5;
    float bv = bias[f];
    float a1 = 0.f, a2 = 0.f;
    for (int n = blockIdx.x * 8 + g; n < N_NODES; n += gridDim.x * 8) {
        int lo = off[n], hi = off[n + 1];
        float acc0 = 0.f, acc1 = 0.f;
        int p = lo;
        for (; p + 1 < hi; p += 2) {
            int2 e0 = epk[p], e1 = epk[p + 1];
            acc0 += bfr(Au[(long)e0.x * 32 + f]) * __int_as_float(e0.y);
            acc1 += bfr(Au[(long)e1.x * 32 + f]) * __int_as_float(e1.y);
        }
        if (p < hi) {
            int2 e0 = epk[p];
            acc0 += bfr(Au[(long)e0.x * 32 + f]) * __int_as_float(e0.y);
        }
        float self = bfr(Au[(long)n * 32 + f]) / (deg[n] + 1.0f);
        float v = fmaxf(acc0 + acc1 + self + bv, 0.f);
        B[(long)n * 32 + f] = __float2bfloat16(v);
        a1 += v; a2 += v * v;
    }
    s1[tid] = a1; s2[tid] = a2; __syncthreads();
    for (int st = 128; st >= 32; st >>= 1) {
        if (tid < st) { s1[tid] += s1[tid + st]; s2[tid] += s2[tid + st]; }
        __syncthreads();
    }
    if (tid < 32) { atomicAdd(&sum[f], s1[f]); atomicAdd(&sq[f], s2[f]); }
}

// ---- BN1 finalize ----------------------------------------------------------
__global__ void k_fin1(const float* __restrict__ sum, const float* __restrict__ sq,
                       const float* __restrict__ g, const float* __restrict__ be,
                       float* __restrict__ scale, float* __restrict__ shift) {
    int t = threadIdx.x;
    if (t < 32) {
        float mu = sum[t] / (float)N_NODES;
        float var = sq[t] / (float)N_NODES - mu * mu;
        float rs = rsqrtf(var + BN_EPS) * g[t];
        scale[t] = rs;
        shift[t] = be[t] - mu * rs;
    }
}

// ---- H = affine(B) (bf16); A = H @ W2 (bf16) -------------------------------
__global__ void k_aff_xw(const bf16* __restrict__ B, const float* __restrict__ scale,
                         const float* __restrict__ shift, const float* __restrict__ w,
                         bf16* __restrict__ H, bf16* __restrict__ A) {
    __shared__ float Ws[32 * 33];
    __shared__ float hs[256];
    for (int i = threadIdx.x; i < 1024; i += 256)
        Ws[(i >> 5) * 33 + (i & 31)] = w[i];
    long base = (long)blockIdx.x * 256;
    int f = threadIdx.x & 31;
    float h = b2f(B[base + threadIdx.x]) * scale[f] + shift[f];
    H[base + threadIdx.x] = __float2bfloat16(h);
    hs[threadIdx.x] = h;
    __syncthreads();
    int r = threadIdx.x >> 5, hc = threadIdx.x & 31;
    float acc = 0.f;
#pragma unroll
    for (int k = 0; k < 32; k++) acc += hs[r * 32 + k] * Ws[k * 33 + hc];
    A[base + threadIdx.x] = __float2bfloat16(acc);
}

// ---- BN2 finalize + fc1 const + combined LSTM biases -----------------------
__global__ void k_fin2(const float* __restrict__ sum, const float* __restrict__ sq,
                       const float* __restrict__ g, const float* __restrict__ be,
                       const float* __restrict__ xsum, const float* __restrict__ fw1,
                       const float* __restrict__ fb1,
                       const float* __restrict__ bih1, const float* __restrict__ bhh1,
                       const float* __restrict__ bih2, const float* __restrict__ bhh2,
                       float* __restrict__ scale, float* __restrict__ shift,
                       float* __restrict__ fc1c, float* __restrict__ lb1,
                       float* __restrict__ lb2) {
    int t = threadIdx.x;
    if (t < 32) {
        float mu = sum[t] / (float)N_NODES;
        float var = sq[t] / (float)N_NODES - mu * mu;
        float rs = rsqrtf(var + BN_EPS) * g[t];
        scale[t] = rs;
        shift[t] = be[t] - mu * rs;
        float c = fb1[t];
        for (int f = 0; f < 32; f++)
            c += (xsum[f] / (float)N_NODES) * fw1[t * 96 + 64 + f];
        fc1c[t] = c;
    }
    if (t < 128) {
        lb1[t] = bih1[t] + bhh1[t];
        lb2[t] = bih2[t] + bhh2[t];
    }
}

// ---- per-node dense stack: bf16-packed LDS weights, 2 nodes/thread --------
// Each b128 LDS read = 8 bf16 weights, amortized over 2 nodes:
// 4 unpack + 8 pk_fma per 12-cyc read (was 2 pk_fma per read in fp32/NPT=1).
__global__ __launch_bounds__(128, 2) void k_final(
    const bf16* __restrict__ Hb, const bf16* __restrict__ Bb,
    const float* __restrict__ scale2, const float* __restrict__ shift2,
    const float* __restrict__ wih1, const float* __restrict__ wih2,
    const float* __restrict__ fw1, const float* __restrict__ fw2,
    const float* __restrict__ fb2,
    const float* __restrict__ fc1c, const float* __restrict__ lb1,
    const float* __restrict__ lb2, float* __restrict__ out) {
    __shared__ uint4 Wa4[768];   // LSTM1 bf16x8: i rows 0..255, g 256..511, o 512..767
    __shared__ uint4 Wb4[384];   // LSTM2: i 0..127, g 128..255, o 256..383
    __shared__ uint4 Fc4[256];   // fc1 rows j (k 0..63): j*8+q
    __shared__ float lb1s[128], lb2s[128], fc1s[32], fw2s[32], sc2[32], sh2[32];
    int tid = threadIdx.x;
    for (int i = tid; i < 768; i += 128) {
        int t = i >> 8, rem = i & 255, c = rem >> 3, q = rem & 7;
        int row = (t == 0) ? c : ((t == 1) ? c + 64 : c + 96);
        const float* b = wih1 + row * 64 + q * 8;
        Wa4[i] = make_uint4(pk2(b), pk2(b + 2), pk2(b + 4), pk2(b + 6));
    }
    for (int i = tid; i < 384; i += 128) {
        int t = i >> 7, rem = i & 127, c = rem >> 2, q = rem & 3;
        int row = (t == 0) ? c : ((t == 1) ? c + 64 : c + 96);
        const float* b = wih2 + row * 32 + q * 8;
        Wb4[i] = make_uint4(pk2(b), pk2(b + 2), pk2(b + 4), pk2(b + 6));
    }
    for (int i = tid; i < 256; i += 128) {
        int j = i >> 3, q = i & 7;
        const float* b = fw1 + j * 96 + q * 8;
        Fc4[i] = make_uint4(pk2(b), pk2(b + 2), pk2(b + 4), pk2(b + 6));
    }
    if (tid < 128) { lb1s[tid] = lb1[tid]; lb2s[tid] = lb2[tid]; }
    if (tid < 32) {
        fc1s[tid] = fc1c[tid]; fw2s[tid] = fw2[tid];
        sc2[tid] = scale2[tid]; sh2[tid] = shift2[tid];
    }
    __syncthreads();
    int n0 = blockIdx.x * 256 + tid;
    int n1 = n0 + 128;
    int n1c = (n1 < N_NODES) ? n1 : n0;

    v2f c0[32], c1[32];
    {
        const uint4* Hv0 = (const uint4*)((const ushort*)Hb + (long)n0 * 32);
        const uint4* Bv0 = (const uint4*)((const ushort*)Bb + (long)n0 * 32);
        const uint4* Hv1 = (const uint4*)((const ushort*)Hb + (long)n1c * 32);
        const uint4* Bv1 = (const uint4*)((const ushort*)Bb + (long)n1c * 32);
#pragma unroll
        for (int q = 0; q < 4; q++) {
            uint4 h0 = Hv0[q], b0 = Bv0[q], h1 = Hv1[q], b1 = Bv1[q];
            uint hw0[4] = {h0.x, h0.y, h0.z, h0.w}, bw0[4] = {b0.x, b0.y, b0.z, b0.w};
            uint hw1[4] = {h1.x, h1.y, h1.z, h1.w}, bw1[4] = {b1.x, b1.y, b1.z, b1.w};
#pragma unroll
            for (int r = 0; r < 4; r++) {
                int u = q * 4 + r;
                int e0 = 2 * u, e1 = 2 * u + 1;
                v2f sc = (v2f){sc2[e0], sc2[e1]}, sh = (v2f){sh2[e0], sh2[e1]};
                c0[u] = up(hw0[r]);
                c1[u] = up(hw1[r]);
                c0[16 + u] = vfma(up(bw0[r]), sc, sh);
                c1[16 + u] = vfma(up(bw1[r]), sc, sh);
            }
        }
    }
    v2f h10[16], h11[16];
#pragma unroll
    for (int c = 0; c < 32; c++) {
        v2f ai0 = (v2f)0.f, ag0 = (v2f)0.f, ao0 = (v2f)0.f;
        v2f ai1 = (v2f)0.f, ag1 = (v2f)0.f, ao1 = (v2f)0.f;
#pragma unroll
        for (int q = 0; q < 8; q++) {
            uint4 wi = Wa4[c * 8 + q], wg = Wa4[256 + c * 8 + q], wo = Wa4[512 + c * 8 + q];
            uint wiw[4] = {wi.x, wi.y, wi.z, wi.w};
            uint wgw[4] = {wg.x, wg.y, wg.z, wg.w};
            uint wow[4] = {wo.x, wo.y, wo.z, wo.w};
#pragma unroll
            for (int r = 0; r < 4; r++) {
                v2f x0 = c0[q * 4 + r], x1 = c1[q * 4 + r];
                v2f p = up(wiw[r]); ai0 = vfma(p, x0, ai0); ai1 = vfma(p, x1, ai1);
                p = up(wgw[r]);     ag0 = vfma(p, x0, ag0); ag1 = vfma(p, x1, ag1);
                p = up(wow[r]);     ao0 = vfma(p, x0, ao0); ao1 = vfma(p, x1, ao1);
            }
        }
        float gi0 = ai0.x + ai0.y + lb1s[c], gg0 = ag0.x + ag0.y + lb1s[64 + c];
        float go0 = ao0.x + ao0.y + lb1s[96 + c];
        float gi1 = ai1.x + ai1.y + lb1s[c], gg1 = ag1.x + ag1.y + lb1s[64 + c];
        float go1 = ao1.x + ao1.y + lb1s[96 + c];
        float cc0 = fsig(gi0) * ftanh(gg0), cc1 = fsig(gi1) * ftanh(gg1);
        h10[c >> 1][c & 1] = fsig(go0) * ftanh(cc0);
        h11[c >> 1][c & 1] = fsig(go1) * ftanh(cc1);
    }
    v2f h20[16], h21[16];
#pragma unroll
    for (int c = 0; c < 32; c++) {
        v2f ai0 = (v2f)0.f, ag0 = (v2f)0.f, ao0 = (v2f)0.f;
        v2f ai1 = (v2f)0.f, ag1 = (v2f)0.f, ao1 = (v2f)0.f;
#pragma unroll
        for (int q = 0; q < 4; q++) {
            uint4 wi = Wb4[c * 4 + q], wg = Wb4[128 + c * 4 + q], wo = Wb4[256 + c * 4 + q];
            uint wiw[4] = {wi.x, wi.y, wi.z, wi.w};
            uint wgw[4] = {wg.x, wg.y, wg.z, wg.w};
            uint wow[4] = {wo.x, wo.y, wo.z, wo.w};
#pragma unroll
            for (int r = 0; r < 4; r++) {
                v2f x0 = h10[q * 4 + r], x1 = h11[q * 4 + r];
                v2f p = up(wiw[r]); ai0 = vfma(p, x0, ai0); ai1 = vfma(p, x1, ai1);
                p = up(wgw[r]);     ag0 = vfma(p, x0, ag0); ag1 = vfma(p, x1, ag1);
                p = up(wow[r]);     ao0 = vfma(p, x0, ao0); ao1 = vfma(p, x1, ao1);
            }
        }
        float gi0 = ai0.x + ai0.y + lb2s[c], gg0 = ag0.x + ag0.y + lb2s[64 + c];
        float go0 = ao0.x + ao0.y + lb2s[96 + c];
        float gi1 = ai1.x + ai1.y + lb2s[c], gg1 = ag1.x + ag1.y + lb2s[64 + c];
        float go1 = ao1.x + ao1.y + lb2s[96 + c];
        float cc0 = fsig(gi0) * ftanh(gg0), cc1 = fsig(gi1) * ftanh(gg1);
        h20[c >> 1][c & 1] = fsig(go0) * ftanh(cc0);
        h21[c >> 1][c & 1] = fsig(go1) * ftanh(cc1);
    }
    float fb2v = fb2[0];
    float acc0 = fb2v, acc1 = fb2v;
#pragma unroll
    for (int j = 0; j < 32; j++) {
        v2f z0 = (v2f)0.f, z1 = (v2f)0.f;
#pragma unroll
        for (int q = 0; q < 8; q++) {
            uint4 w = Fc4[j * 8 + q];
            uint ww[4] = {w.x, w.y, w.z, w.w};
#pragma unroll
            for (int r = 0; r < 4; r++) {
                v2f p = up(ww[r]);
                v2f y0 = (q < 4) ? h10[q * 4 + r] : h20[(q - 4) * 4 + r];
                v2f y1 = (q < 4) ? h11[q * 4 + r] : h21[(q - 4) * 4 + r];
                z0 = vfma(p, y0, z0); z1 = vfma(p, y1, z1);
            }
        }
        float zz0 = z0.x + z0.y + fc1s[j], zz1 = z1.x + z1.y + fc1s[j];
        acc0 += fmaxf(zz0, 0.f) * fw2s[j];
        acc1 += fmaxf(zz1, 0.f) * fw2s[j];
    }
    out[n0] = acc0;
    if (n1 < N_NODES) out[n1] = acc1;
}

extern "C" void kernel_launch(void* const* d_in, const int* in_sizes, int n_in,
                              void* d_out, int out_size, void* d_ws, size_t ws_size,
                              hipStream_t stream) {
    const float* x    = (const float*)d_in[0];
    const int*   ei   = (const int*)d_in[1];
    const float* ew   = (const float*)d_in[2];
    const float* w1   = (const float*)d_in[3];
    const float* b1   = (const float*)d_in[4];
    const float* g1   = (const float*)d_in[5];
    const float* be1  = (const float*)d_in[6];
    const float* w2   = (const float*)d_in[7];
    const float* b2   = (const float*)d_in[8];
    const float* g2   = (const float*)d_in[9];
    const float* be2  = (const float*)d_in[10];
    const float* wih1 = (const float*)d_in[11];
    const float* bih1 = (const float*)d_in[13];
    const float* bhh1 = (const float*)d_in[14];
    const float* wih2 = (const float*)d_in[15];
    const float* bih2 = (const float*)d_in[17];
    const float* bhh2 = (const float*)d_in[18];
    const float* fw1  = (const float*)d_in[19];
    const float* fb1  = (const float*)d_in[20];
    const float* fw2  = (const float*)d_in[21];
    const float* fb2  = (const float*)d_in[22];
    float* out = (float*)d_out;

    // ---- workspace layout (40.5 MB; proven ws >= 41.1 MB from r3/r4) -------
    char* ws = (char*)d_ws;
    float* stats = (float*)ws;                          // 576 floats @ 0
    float* xsum   = stats + 0;
    float* bn1sum = stats + 32;
    float* bn1sq  = stats + 64;
    float* bn2sum = stats + 96;
    float* bn2sq  = stats + 128;
    float* scale1 = stats + 160;
    float* shift1 = stats + 192;
    float* scale2 = stats + 224;
    float* shift2 = stats + 256;
    float* fc1c   = stats + 288;
    float* lb1    = stats + 320;
    float* lb2    = stats + 448;
    ull*   pk    = (ull*)  (ws + 4096);                 // 100000 ull -> 804,096
    int*   bsum  = (int*)  (ws + 804096);               // 391 i
    int*   bbase = (int*)  (ws + 808192);               // 391 i
    int*   off   = (int*)  (ws + 1048576);              // 100001 i -> 1,448,580
    float* deg   = (float*)(ws + 1572864);              // 100000 f -> 1,972,864
    int2*  epk   = (int2*) (ws + 2097152);              // 1.6M int2 -> 14,897,152
    int*   rank  = (int*)  (ws + 14897152);             // 1.6M i -> 21,297,152
    bf16*  A     = (bf16*) (ws + 21297152);             // 6.4MB -> 27,697,152
    bf16*  H     = (bf16*) (ws + 27697152);             // 6.4MB -> 34,097,152
    bf16*  B     = (bf16*) (ws + 34097152);             // 6.4MB -> 40,497,152

    if (ws_size < 40497152ull) {
        k_marker<<<(N_NODES + 255) / 256, 256, 0, stream>>>(out, N_NODES, 911.f);
        return;
    }

    // zero stats + pk in one shot (bytes 0 .. 804,096)
    k_zero_f<<<786, 256, 0, stream>>>(stats, 201024);

    k_hist<<<6250, 256, 0, stream>>>(ei, ew, pk, rank);
    k_bsum<<<SCAN_BLOCKS, 256, 0, stream>>>(pk, bsum);
    k_bscan<<<1, 512, 0, stream>>>(bsum, bbase);
    k_scan3<<<SCAN_BLOCKS, 256, 0, stream>>>(pk, bbase, off, deg);
    k_scatter<<<6250, 256, 0, stream>>>(ei, ew, deg, off, rank, epk);
    k_xmean<<<400, 256, 0, stream>>>(x, xsum);
    k_xw1<<<12500, 256, 0, stream>>>(x, w1, A);
    k_gcn<<<1024, 256, 0, stream>>>(off, epk, A, deg, b1, B, bn1sum, bn1sq);
    k_fin1<<<1, 64, 0, stream>>>(bn1sum, bn1sq, g1, be1, scale1, shift1);
    k_aff_xw<<<12500, 256, 0, stream>>>(B, scale1, shift1, w2, H, A);
    k_gcn<<<1024, 256, 0, stream>>>(off, epk, A, deg, b2, B, bn2sum, bn2sq);
    k_fin2<<<1, 128, 0, stream>>>(bn2sum, bn2sq, g2, be2, xsum, fw1, fb1,
                                  bih1, bhh1, bih2, bhh2,
                                  scale2, shift2, fc1c, lb1, lb2);
    k_final<<<SCAN_BLOCKS, 128, 0, stream>>>(H, B, scale2, shift2, wih1, wih2,
                                             fw1, fw2, fb2, fc1c, lb1, lb2, out);
}

// Round 10
// 543.517 us; speedup vs baseline: 5.3699x; 5.3699x over previous
//
#include <hip/hip_runtime.h>
#include <hip/hip_bf16.h>

#define N_NODES 100000
#define N_EDGES 1600000
#define BN_EPS 1e-5f
#define SCAN_BLOCKS 391   // ceil(100000/256)

typedef __hip_bfloat16 bf16;
typedef unsigned long long ull;
typedef float v2f __attribute__((ext_vector_type(2)));

__device__ __forceinline__ float b2f(bf16 v) { return __bfloat162float(v); }
__device__ __forceinline__ float frcp(float x) { return __builtin_amdgcn_rcpf(x); }
__device__ __forceinline__ float fsig(float x) { return frcp(1.0f + __expf(-x)); }
__device__ __forceinline__ float ftanh(float x) {
    return 1.0f - 2.0f * frcp(__expf(2.0f * x) + 1.0f);
}
__device__ __forceinline__ float bfr(uint u) { return __uint_as_float(u << 16); }
__device__ __forceinline__ v2f up(uint u) {
    return (v2f){__uint_as_float(u << 16), __uint_as_float(u & 0xffff0000u)};
}
__device__ __forceinline__ v2f vfma(v2f a, v2f b, v2f c) {
    return __builtin_elementwise_fma(a, b, c);
}
__device__ __forceinline__ uint pk2(const float* p) {
    bf16 a = __float2bfloat16(p[0]), b = __float2bfloat16(p[1]);
    return (uint)*(ushort*)&a | ((uint)*(ushort*)&b << 16);
}

// ---- utility ---------------------------------------------------------------
__global__ void k_zero_f(float* __restrict__ p, int n) {
    int i = blockIdx.x * 256 + threadIdx.x;
    if (i < n) p[i] = 0.f;
}
__global__ void k_marker(float* __restrict__ p, int n, float v) {
    int i = blockIdx.x * 256 + threadIdx.x;
    if (i < n) p[i] = v;
}

// ---- packed histogram: pk[d] += (1<<48)|fx(ew); rank = old count -----------
__global__ void k_hist(const int* __restrict__ ei, const float* __restrict__ ew,
                       ull* __restrict__ pk, int* __restrict__ rank) {
    int e = blockIdx.x * 256 + threadIdx.x;
    if (e < N_EDGES) {
        int d = ei[N_EDGES + e];
        ull v = (1ull << 48) | (ull)((double)ew[e] * 4294967296.0);
        ull old = atomicAdd(&pk[d], v);
        rank[e] = (int)(old >> 48);
    }
}

// ---- parallel scan, stage 1: per-block sums of counts ----------------------
__global__ void k_bsum(const ull* __restrict__ pk, int* __restrict__ bsum) {
    __shared__ int s[256];
    int idx = blockIdx.x * 256 + threadIdx.x;
    s[threadIdx.x] = (idx < N_NODES) ? (int)(pk[idx] >> 48) : 0;
    __syncthreads();
    for (int st = 128; st >= 1; st >>= 1) {
        if (threadIdx.x < st) s[threadIdx.x] += s[threadIdx.x + st];
        __syncthreads();
    }
    if (threadIdx.x == 0) bsum[blockIdx.x] = s[0];
}

// ---- stage 2: exclusive scan of 391 block sums (single tiny block) ---------
__global__ __launch_bounds__(512) void k_bscan(const int* __restrict__ bsum,
                                               int* __restrict__ bbase) {
    __shared__ int s[512];
    int t = threadIdx.x;
    int v = (t < SCAN_BLOCKS) ? bsum[t] : 0;
    s[t] = v; __syncthreads();
    for (int st = 1; st < 512; st <<= 1) {
        int u = (t >= st) ? s[t - st] : 0;
        __syncthreads();
        s[t] += u;
        __syncthreads();
    }
    if (t < SCAN_BLOCKS) bbase[t] = s[t] - v;   // exclusive prefix
}

// ---- stage 3: block scan -> off; unpack deg from pk ------------------------
__global__ void k_scan3(const ull* __restrict__ pk, const int* __restrict__ bbase,
                        int* __restrict__ off, float* __restrict__ deg) {
    __shared__ int wsum[4];
    int idx = blockIdx.x * 256 + threadIdx.x;
    int lane = threadIdx.x & 63, w = threadIdx.x >> 6;
    ull pv = (idx < N_NODES) ? pk[idx] : 0ull;
    int c = (int)(pv >> 48);
    int s = c;
    for (int d = 1; d < 64; d <<= 1) {
        int u = __shfl_up(s, d, 64);
        if (lane >= d) s += u;
    }
    if (lane == 63) wsum[w] = s;
    __syncthreads();
    int wb = 0;
    for (int i = 0; i < w; i++) wb += wsum[i];
    int e = bbase[blockIdx.x] + wb + s - c;      // exclusive
    if (idx < N_NODES) {
        off[idx] = e;
        deg[idx] = (float)((double)(pv & 0xFFFFFFFFFFFFull) * (1.0 / 4294967296.0));
    }
    if (idx == 0) off[N_NODES] = N_EDGES;        // all dst are in-range
}

// ---- scatter edges into CSR slots as {src, norm} — NO atomics --------------
__global__ void k_scatter(const int* __restrict__ ei, const float* __restrict__ ew,
                          const float* __restrict__ deg, const int* __restrict__ off,
                          const int* __restrict__ rank, int2* __restrict__ epk) {
    int e = blockIdx.x * 256 + threadIdx.x;
    if (e < N_EDGES) {
        int s = ei[e], d = ei[N_EDGES + e];
        float nm = ew[e] * rsqrtf((deg[s] + 1.0f) * (deg[d] + 1.0f));
        epk[off[d] + rank[e]] = make_int2(s, __float_as_int(nm));
    }
}

// ---- column sums of x (for skip_avg) ---------------------------------------
__global__ void k_xmean(const float* __restrict__ x, float* __restrict__ xsum) {
    __shared__ float s[256];
    int f = threadIdx.x & 31, rg = threadIdx.x >> 5;
    float acc = 0.f;
    for (int n = blockIdx.x * 8 + rg; n < N_NODES; n += gridDim.x * 8)
        acc += x[n * 32 + f];
    s[threadIdx.x] = acc; __syncthreads();
    for (int st = 128; st >= 32; st >>= 1) {
        if (threadIdx.x < st) s[threadIdx.x] += s[threadIdx.x + st];
        __syncthreads();
    }
    if (threadIdx.x < 32) atomicAdd(&xsum[threadIdx.x], s[threadIdx.x]);
}

// ---- A = x @ W1 (fp32 in, bf16 out) ----------------------------------------
__global__ void k_xw1(const float* __restrict__ x, const float* __restrict__ w,
                      bf16* __restrict__ A) {
    __shared__ float Ws[32 * 33];
    __shared__ float xs[256];
    for (int i = threadIdx.x; i < 1024; i += 256)
        Ws[(i >> 5) * 33 + (i & 31)] = w[i];
    long base = (long)blockIdx.x * 256;
    xs[threadIdx.x] = x[base + threadIdx.x];
    __syncthreads();
    int r = threadIdx.x >> 5, h = threadIdx.x & 31;
    float acc = 0.f;
#pragma unroll
    for (int f = 0; f < 32; f++) acc += xs[r * 32 + f] * Ws[f * 33 + h];
    A[base + threadIdx.x] = __float2bfloat16(acc);
}

// ---- pull-mode GCN: agg + self-loop + bias + relu + BN stats ---------------
__global__ __launch_bounds__(256) void k_gcn(
    const int* __restrict__ off, const int2* __restrict__ epk,
    const bf16* __restrict__ A, const float* __restrict__ deg,
    const float* __restrict__ bias, bf16* __restrict__ B,
    float* __restrict__ sum, float* __restrict__ sq) {
    __shared__ float s1[256], s2[256];
    const ushort* Au = (const ushort*)A;
    int tid = threadIdx.x, f = tid & 31, g = tid >> 5;
    float bv = bias[f];
    float a1 = 0.f, a2 = 0.f;
    for (int n = blockIdx.x * 8 + g; n < N_NODES; n += gridDim.x * 8) {
        int lo = off[n], hi = off[n + 1];
        float acc0 = 0.f, acc1 = 0.f;
        int p = lo;
        for (; p + 1 < hi; p += 2) {
            int2 e0 = epk[p], e1 = epk[p + 1];
            acc0 += bfr(Au[(long)e0.x * 32 + f]) * __int_as_float(e0.y);
            acc1 += bfr(Au[(long)e1.x * 32 + f]) * __int_as_float(e1.y);
        }
        if (p < hi) {
            int2 e0 = epk[p];
            acc0 += bfr(Au[(long)e0.x * 32 + f]) * __int_as_float(e0.y);
        }
        float self = bfr(Au[(long)n * 32 + f]) / (deg[n] + 1.0f);
        float v = fmaxf(acc0 + acc1 + self + bv, 0.f);
        B[(long)n * 32 + f] = __float2bfloat16(v);
        a1 += v; a2 += v * v;
    }
    s1[tid] = a1; s2[tid] = a2; __syncthreads();
    for (int st = 128; st >= 32; st >>= 1) {
        if (tid < st) { s1[tid] += s1[tid + st]; s2[tid] += s2[tid + st]; }
        __syncthreads();
    }
    if (tid < 32) { atomicAdd(&sum[f], s1[f]); atomicAdd(&sq[f], s2[f]); }
}

// ---- BN1 finalize ----------------------------------------------------------
__global__ void k_fin1(const float* __restrict__ sum, const float* __restrict__ sq,
                       const float* __restrict__ g, const float* __restrict__ be,
                       float* __restrict__ scale, float* __restrict__ shift) {
    int t = threadIdx.x;
    if (t < 32) {
        float mu = sum[t] / (float)N_NODES;
        float var = sq[t] / (float)N_NODES - mu * mu;
        float rs = rsqrtf(var + BN_EPS) * g[t];
        scale[t] = rs;
        shift[t] = be[t] - mu * rs;
    }
}

// ---- H = affine(B) (bf16); A = H @ W2 (bf16) -------------------------------
__global__ void k_aff_xw(const bf16* __restrict__ B, const float* __restrict__ scale,
                         const float* __restrict__ shift, const float* __restrict__ w,
                         bf16* __restrict__ H, bf16* __restrict__ A) {
    __shared__ float Ws[32 * 33];
    __shared__ float hs[256];
    for (int i = threadIdx.x; i < 1024; i += 256)
        Ws[(i >> 5) * 33 + (i & 31)] = w[i];
    long base = (long)blockIdx.x * 256;
    int f = threadIdx.x & 31;
    float h = b2f(B[base + threadIdx.x]) * scale[f] + shift[f];
    H[base + threadIdx.x] = __float2bfloat16(h);
    hs[threadIdx.x] = h;
    __syncthreads();
    int r = threadIdx.x >> 5, hc = threadIdx.x & 31;
    float acc = 0.f;
#pragma unroll
    for (int k = 0; k < 32; k++) acc += hs[r * 32 + k] * Ws[k * 33 + hc];
    A[base + threadIdx.x] = __float2bfloat16(acc);
}

// ---- BN2 finalize + fc1 const + combined LSTM biases -----------------------
__global__ void k_fin2(const float* __restrict__ sum, const float* __restrict__ sq,
                       const float* __restrict__ g, const float* __restrict__ be,
                       const float* __restrict__ xsum, const float* __restrict__ fw1,
                       const float* __restrict__ fb1,
                       const float* __restrict__ bih1, const float* __restrict__ bhh1,
                       const float* __restrict__ bih2, const float* __restrict__ bhh2,
                       float* __restrict__ scale, float* __restrict__ shift,
                       float* __restrict__ fc1c, float* __restrict__ lb1,
                       float* __restrict__ lb2) {
    int t = threadIdx.x;
    if (t < 32) {
        float mu = sum[t] / (float)N_NODES;
        float var = sq[t] / (float)N_NODES - mu * mu;
        float rs = rsqrtf(var + BN_EPS) * g[t];
        scale[t] = rs;
        shift[t] = be[t] - mu * rs;
        float c = fb1[t];
        for (int f = 0; f < 32; f++)
            c += (xsum[f] / (float)N_NODES) * fw1[t * 96 + 64 + f];
        fc1c[t] = c;
    }
    if (t < 128) {
        lb1[t] = bih1[t] + bhh1[t];
        lb2[t] = bih2[t] + bhh2[t];
    }
}

// ---- per-node dense stack: bf16-packed LDS weights, 1 node/thread ----------
// NPT=1 (r9's NPT=2 spilled: ~260 live VGPRs vs 128 cap -> 2.2 GB scratch).
// Each b128 LDS read = 8 bf16 weights -> 4 unpack + 4 pk_fma per read,
// half the LDS issues of the fp32 variant (r8: 110 us, LDS-issue bound).
__global__ __launch_bounds__(128) void k_final(
    const bf16* __restrict__ Hb, const bf16* __restrict__ Bb,
    const float* __restrict__ scale2, const float* __restrict__ shift2,
    const float* __restrict__ wih1, const float* __restrict__ wih2,
    const float* __restrict__ fw1, const float* __restrict__ fw2,
    const float* __restrict__ fb2,
    const float* __restrict__ fc1c, const float* __restrict__ lb1,
    const float* __restrict__ lb2, float* __restrict__ out) {
    __shared__ uint4 Wa4[768];   // LSTM1 bf16x8: i rows 0..255, g 256..511, o 512..767
    __shared__ uint4 Wb4[384];   // LSTM2: i 0..127, g 128..255, o 256..383
    __shared__ uint4 Fc4[256];   // fc1 rows j (k 0..63): j*8+q
    __shared__ float lb1s[128], lb2s[128], fc1s[32], fw2s[32], sc2[32], sh2[32];
    int tid = threadIdx.x;
    for (int i = tid; i < 768; i += 128) {
        int t = i >> 8, rem = i & 255, c = rem >> 3, q = rem & 7;
        int row = (t == 0) ? c : ((t == 1) ? c + 64 : c + 96);
        const float* b = wih1 + row * 64 + q * 8;
        Wa4[i] = make_uint4(pk2(b), pk2(b + 2), pk2(b + 4), pk2(b + 6));
    }
    for (int i = tid; i < 384; i += 128) {
        int t = i >> 7, rem = i & 127, c = rem >> 2, q = rem & 3;
        int row = (t == 0) ? c : ((t == 1) ? c + 64 : c + 96);
        const float* b = wih2 + row * 32 + q * 8;
        Wb4[i] = make_uint4(pk2(b), pk2(b + 2), pk2(b + 4), pk2(b + 6));
    }
    for (int i = tid; i < 256; i += 128) {
        int j = i >> 3, q = i & 7;
        const float* b = fw1 + j * 96 + q * 8;
        Fc4[i] = make_uint4(pk2(b), pk2(b + 2), pk2(b + 4), pk2(b + 6));
    }
    if (tid < 128) { lb1s[tid] = lb1[tid]; lb2s[tid] = lb2[tid]; }
    if (tid < 32) {
        fc1s[tid] = fc1c[tid]; fw2s[tid] = fw2[tid];
        sc2[tid] = scale2[tid]; sh2[tid] = shift2[tid];
    }
    __syncthreads();
    int n = blockIdx.x * 128 + tid;
    if (n >= N_NODES) return;

    v2f cat2[32];
    {
        const uint4* Hv = (const uint4*)((const ushort*)Hb + (long)n * 32);
        const uint4* Bv = (const uint4*)((const ushort*)Bb + (long)n * 32);
#pragma unroll
        for (int q = 0; q < 4; q++) {
            uint4 hu = Hv[q], bu = Bv[q];
            uint hw[4] = {hu.x, hu.y, hu.z, hu.w};
            uint bw[4] = {bu.x, bu.y, bu.z, bu.w};
#pragma unroll
            for (int r = 0; r < 4; r++) {
                int u = q * 4 + r;
                int e0 = 2 * u, e1 = 2 * u + 1;
                cat2[u] = up(hw[r]);
                cat2[16 + u] = vfma(up(bw[r]),
                                    (v2f){sc2[e0], sc2[e1]},
                                    (v2f){sh2[e0], sh2[e1]});
            }
        }
    }
    v2f h1[16];
#pragma unroll
    for (int c = 0; c < 32; c++) {
        v2f ai = (v2f)0.f, ag = (v2f)0.f, ao = (v2f)0.f;
#pragma unroll
        for (int q = 0; q < 8; q++) {
            uint4 wi = Wa4[c * 8 + q], wg = Wa4[256 + c * 8 + q], wo = Wa4[512 + c * 8 + q];
            uint wiw[4] = {wi.x, wi.y, wi.z, wi.w};
            uint wgw[4] = {wg.x, wg.y, wg.z, wg.w};
            uint wow[4] = {wo.x, wo.y, wo.z, wo.w};
#pragma unroll
            for (int r = 0; r < 4; r++) {
                v2f x0 = cat2[q * 4 + r];
                ai = vfma(up(wiw[r]), x0, ai);
                ag = vfma(up(wgw[r]), x0, ag);
                ao = vfma(up(wow[r]), x0, ao);
            }
        }
        float gi = ai.x + ai.y + lb1s[c];
        float gg = ag.x + ag.y + lb1s[64 + c];
        float go = ao.x + ao.y + lb1s[96 + c];
        float c1 = fsig(gi) * ftanh(gg);
        h1[c >> 1][c & 1] = fsig(go) * ftanh(c1);
    }
    v2f h2[16];
#pragma unroll
    for (int c = 0; c < 32; c++) {
        v2f ai = (v2f)0.f, ag = (v2f)0.f, ao = (v2f)0.f;
#pragma unroll
        for (int q = 0; q < 4; q++) {
            uint4 wi = Wb4[c * 4 + q], wg = Wb4[128 + c * 4 + q], wo = Wb4[256 + c * 4 + q];
            uint wiw[4] = {wi.x, wi.y, wi.z, wi.w};
            uint wgw[4] = {wg.x, wg.y, wg.z, wg.w};
            uint wow[4] = {wo.x, wo.y, wo.z, wo.w};
#pragma unroll
            for (int r = 0; r < 4; r++) {
                v2f x0 = h1[q * 4 + r];
                ai = vfma(up(wiw[r]), x0, ai);
                ag = vfma(up(wgw[r]), x0, ag);
                ao = vfma(up(wow[r]), x0, ao);
            }
        }
        float gi = ai.x + ai.y + lb2s[c];
        float gg = ag.x + ag.y + lb2s[64 + c];
        float go = ao.x + ao.y + lb2s[96 + c];
        float c2 = fsig(gi) * ftanh(gg);
        h2[c >> 1][c & 1] = fsig(go) * ftanh(c2);
    }
    float acc = fb2[0];
#pragma unroll
    for (int j = 0; j < 32; j++) {
        v2f z = (v2f)0.f;
#pragma unroll
        for (int q = 0; q < 8; q++) {
            uint4 w = Fc4[j * 8 + q];
            uint ww[4] = {w.x, w.y, w.z, w.w};
#pragma unroll
            for (int r = 0; r < 4; r++) {
                v2f y = (q < 4) ? h1[q * 4 + r] : h2[(q - 4) * 4 + r];
                z = vfma(up(ww[r]), y, z);
            }
        }
        float zz = z.x + z.y + fc1s[j];
        acc += fmaxf(zz, 0.f) * fw2s[j];
    }
    out[n] = acc;
}

extern "C" void kernel_launch(void* const* d_in, const int* in_sizes, int n_in,
                              void* d_out, int out_size, void* d_ws, size_t ws_size,
                              hipStream_t stream) {
    const float* x    = (const float*)d_in[0];
    const int*   ei   = (const int*)d_in[1];
    const float* ew   = (const float*)d_in[2];
    const float* w1   = (const float*)d_in[3];
    const float* b1   = (const float*)d_in[4];
    const float* g1   = (const float*)d_in[5];
    const float* be1  = (const float*)d_in[6];
    const float* w2   = (const float*)d_in[7];
    const float* b2   = (const float*)d_in[8];
    const float* g2   = (const float*)d_in[9];
    const float* be2  = (const float*)d_in[10];
    const float* wih1 = (const float*)d_in[11];
    const float* bih1 = (const float*)d_in[13];
    const float* bhh1 = (const float*)d_in[14];
    const float* wih2 = (const float*)d_in[15];
    const float* bih2 = (const float*)d_in[17];
    const float* bhh2 = (const float*)d_in[18];
    const float* fw1  = (const float*)d_in[19];
    const float* fb1  = (const float*)d_in[20];
    const float* fw2  = (const float*)d_in[21];
    const float* fb2  = (const float*)d_in[22];
    float* out = (float*)d_out;

    // ---- workspace layout (40.5 MB; proven ws >= 41.1 MB from r3/r4) -------
    char* ws = (char*)d_ws;
    float* stats = (float*)ws;                          // 576 floats @ 0
    float* xsum   = stats + 0;
    float* bn1sum = stats + 32;
    float* bn1sq  = stats + 64;
    float* bn2sum = stats + 96;
    float* bn2sq  = stats + 128;
    float* scale1 = stats + 160;
    float* shift1 = stats + 192;
    float* scale2 = stats + 224;
    float* shift2 = stats + 256;
    float* fc1c   = stats + 288;
    float* lb1    = stats + 320;
    float* lb2    = stats + 448;
    ull*   pk    = (ull*)  (ws + 4096);                 // 100000 ull -> 804,096
    int*   bsum  = (int*)  (ws + 804096);               // 391 i
    int*   bbase = (int*)  (ws + 808192);               // 391 i
    int*   off   = (int*)  (ws + 1048576);              // 100001 i -> 1,448,580
    float* deg   = (float*)(ws + 1572864);              // 100000 f -> 1,972,864
    int2*  epk   = (int2*) (ws + 2097152);              // 1.6M int2 -> 14,897,152
    int*   rank  = (int*)  (ws + 14897152);             // 1.6M i -> 21,297,152
    bf16*  A     = (bf16*) (ws + 21297152);             // 6.4MB -> 27,697,152
    bf16*  H     = (bf16*) (ws + 27697152);             // 6.4MB -> 34,097,152
    bf16*  B     = (bf16*) (ws + 34097152);             // 6.4MB -> 40,497,152

    if (ws_size < 40497152ull) {
        k_marker<<<(N_NODES + 255) / 256, 256, 0, stream>>>(out, N_NODES, 911.f);
        return;
    }

    // zero stats + pk in one shot (bytes 0 .. 804,096)
    k_zero_f<<<786, 256, 0, stream>>>(stats, 201024);

    k_hist<<<6250, 256, 0, stream>>>(ei, ew, pk, rank);
    k_bsum<<<SCAN_BLOCKS, 256, 0, stream>>>(pk, bsum);
    k_bscan<<<1, 512, 0, stream>>>(bsum, bbase);
    k_scan3<<<SCAN_BLOCKS, 256, 0, stream>>>(pk, bbase, off, deg);
    k_scatter<<<6250, 256, 0, stream>>>(ei, ew, deg, off, rank, epk);
    k_xmean<<<400, 256, 0, stream>>>(x, xsum);
    k_xw1<<<12500, 256, 0, stream>>>(x, w1, A);
    k_gcn<<<1024, 256, 0, stream>>>(off, epk, A, deg, b1, B, bn1sum, bn1sq);
    k_fin1<<<1, 64, 0, stream>>>(bn1sum, bn1sq, g1, be1, scale1, shift1);
    k_aff_xw<<<12500, 256, 0, stream>>>(B, scale1, shift1, w2, H, A);
    k_gcn<<<1024, 256, 0, stream>>>(off, epk, A, deg, b2, B, bn2sum, bn2sq);
    k_fin2<<<1, 128, 0, stream>>>(bn2sum, bn2sq, g2, be2, xsum, fw1, fb1,
                                  bih1, bhh1, bih2, bhh2,
                                  scale2, shift2, fc1c, lb1, lb2);
    k_final<<<782, 128, 0, stream>>>(H, B, scale2, shift2, wih1, wih2,
                                     fw1, fw2, fb2, fc1c, lb1, lb2, out);
}

// Round 11
// 480.519 us; speedup vs baseline: 6.0739x; 1.1311x over previous
//
#include <hip/hip_runtime.h>
#include <hip/hip_bf16.h>

#define N_NODES 100000
#define N_EDGES 1600000
#define BN_EPS 1e-5f
#define SCAN_BLOCKS 391   // ceil(100000/256)

typedef __hip_bfloat16 bf16;
typedef unsigned long long ull;
typedef float v2f __attribute__((ext_vector_type(2)));

__device__ __forceinline__ float b2f(bf16 v) { return __bfloat162float(v); }
__device__ __forceinline__ float frcp(float x) { return __builtin_amdgcn_rcpf(x); }
__device__ __forceinline__ float fsig(float x) { return frcp(1.0f + __expf(-x)); }
__device__ __forceinline__ float ftanh(float x) {
    return 1.0f - 2.0f * frcp(__expf(2.0f * x) + 1.0f);
}
__device__ __forceinline__ float bfr(uint u) { return __uint_as_float(u << 16); }
__device__ __forceinline__ v2f up(uint u) {
    return (v2f){__uint_as_float(u << 16), __uint_as_float(u & 0xffff0000u)};
}
__device__ __forceinline__ v2f vfma(v2f a, v2f b, v2f c) {
    return __builtin_elementwise_fma(a, b, c);
}
__device__ __forceinline__ uint pk2(const float* p) {
    bf16 a = __float2bfloat16(p[0]), b = __float2bfloat16(p[1]);
    return (uint)*(ushort*)&a | ((uint)*(ushort*)&b << 16);
}
__device__ __forceinline__ uint pkv(v2f v) {
    bf16 a = __float2bfloat16(v.x), b = __float2bfloat16(v.y);
    return (uint)*(ushort*)&a | ((uint)*(ushort*)&b << 16);
}

// ---- utility ---------------------------------------------------------------
__global__ void k_zero_f(float* __restrict__ p, int n) {
    int i = blockIdx.x * 256 + threadIdx.x;
    if (i < n) p[i] = 0.f;
}
__global__ void k_marker(float* __restrict__ p, int n, float v) {
    int i = blockIdx.x * 256 + threadIdx.x;
    if (i < n) p[i] = v;
}

// ---- packed histogram: pk[d] += (1<<48)|fx(ew); rank = old count -----------
__global__ void k_hist(const int* __restrict__ ei, const float* __restrict__ ew,
                       ull* __restrict__ pk, int* __restrict__ rank) {
    int e = blockIdx.x * 256 + threadIdx.x;
    if (e < N_EDGES) {
        int d = ei[N_EDGES + e];
        ull v = (1ull << 48) | (ull)((double)ew[e] * 4294967296.0);
        ull old = atomicAdd(&pk[d], v);
        rank[e] = (int)(old >> 48);
    }
}

// ---- parallel scan, stage 1: per-block sums of counts ----------------------
__global__ void k_bsum(const ull* __restrict__ pk, int* __restrict__ bsum) {
    __shared__ int s[256];
    int idx = blockIdx.x * 256 + threadIdx.x;
    s[threadIdx.x] = (idx < N_NODES) ? (int)(pk[idx] >> 48) : 0;
    __syncthreads();
    for (int st = 128; st >= 1; st >>= 1) {
        if (threadIdx.x < st) s[threadIdx.x] += s[threadIdx.x + st];
        __syncthreads();
    }
    if (threadIdx.x == 0) bsum[blockIdx.x] = s[0];
}

// ---- stage 2: exclusive scan of 391 block sums (single tiny block) ---------
__global__ __launch_bounds__(512) void k_bscan(const int* __restrict__ bsum,
                                               int* __restrict__ bbase) {
    __shared__ int s[512];
    int t = threadIdx.x;
    int v = (t < SCAN_BLOCKS) ? bsum[t] : 0;
    s[t] = v; __syncthreads();
    for (int st = 1; st < 512; st <<= 1) {
        int u = (t >= st) ? s[t - st] : 0;
        __syncthreads();
        s[t] += u;
        __syncthreads();
    }
    if (t < SCAN_BLOCKS) bbase[t] = s[t] - v;   // exclusive prefix
}

// ---- stage 3: block scan -> off; unpack deg from pk ------------------------
__global__ void k_scan3(const ull* __restrict__ pk, const int* __restrict__ bbase,
                        int* __restrict__ off, float* __restrict__ deg) {
    __shared__ int wsum[4];
    int idx = blockIdx.x * 256 + threadIdx.x;
    int lane = threadIdx.x & 63, w = threadIdx.x >> 6;
    ull pv = (idx < N_NODES) ? pk[idx] : 0ull;
    int c = (int)(pv >> 48);
    int s = c;
    for (int d = 1; d < 64; d <<= 1) {
        int u = __shfl_up(s, d, 64);
        if (lane >= d) s += u;
    }
    if (lane == 63) wsum[w] = s;
    __syncthreads();
    int wb = 0;
    for (int i = 0; i < w; i++) wb += wsum[i];
    int e = bbase[blockIdx.x] + wb + s - c;      // exclusive
    if (idx < N_NODES) {
        off[idx] = e;
        deg[idx] = (float)((double)(pv & 0xFFFFFFFFFFFFull) * (1.0 / 4294967296.0));
    }
    if (idx == 0) off[N_NODES] = N_EDGES;        // all dst are in-range
}

// ---- scatter edges into CSR slots as {src, norm} — NO atomics --------------
__global__ void k_scatter(const int* __restrict__ ei, const float* __restrict__ ew,
                          const float* __restrict__ deg, const int* __restrict__ off,
                          const int* __restrict__ rank, int2* __restrict__ epk) {
    int e = blockIdx.x * 256 + threadIdx.x;
    if (e < N_EDGES) {
        int s = ei[e], d = ei[N_EDGES + e];
        float nm = ew[e] * rsqrtf((deg[s] + 1.0f) * (deg[d] + 1.0f));
        epk[off[d] + rank[e]] = make_int2(s, __float_as_int(nm));
    }
}

// ---- column sums of x (for skip_avg) ---------------------------------------
__global__ void k_xmean(const float* __restrict__ x, float* __restrict__ xsum) {
    __shared__ float s[256];
    int f = threadIdx.x & 31, rg = threadIdx.x >> 5;
    float acc = 0.f;
    for (int n = blockIdx.x * 8 + rg; n < N_NODES; n += gridDim.x * 8)
        acc += x[n * 32 + f];
    s[threadIdx.x] = acc; __syncthreads();
    for (int st = 128; st >= 32; st >>= 1) {
        if (threadIdx.x < st) s[threadIdx.x] += s[threadIdx.x + st];
        __syncthreads();
    }
    if (threadIdx.x < 32) atomicAdd(&xsum[threadIdx.x], s[threadIdx.x]);
}

// ---- A = x @ W1 (fp32 in, bf16 out) ----------------------------------------
__global__ void k_xw1(const float* __restrict__ x, const float* __restrict__ w,
                      bf16* __restrict__ A) {
    __shared__ float Ws[32 * 33];
    __shared__ float xs[256];
    for (int i = threadIdx.x; i < 1024; i += 256)
        Ws[(i >> 5) * 33 + (i & 31)] = w[i];
    long base = (long)blockIdx.x * 256;
    xs[threadIdx.x] = x[base + threadIdx.x];
    __syncthreads();
    int r = threadIdx.x >> 5, h = threadIdx.x & 31;
    float acc = 0.f;
#pragma unroll
    for (int f = 0; f < 32; f++) acc += xs[r * 32 + f] * Ws[f * 33 + h];
    A[base + threadIdx.x] = __float2bfloat16(acc);
}

// ---- pull-mode GCN: 16 lanes/node, uint (2-feature) gathers, unroll 4 ------
__global__ __launch_bounds__(256) void k_gcn(
    const int* __restrict__ off, const int2* __restrict__ epk,
    const bf16* __restrict__ A, const float* __restrict__ deg,
    const float* __restrict__ bias, bf16* __restrict__ B,
    float* __restrict__ sum, float* __restrict__ sq) {
    __shared__ v2f s1[256], s2[256];
    const uint* Au = (const uint*)A;
    uint* Bu = (uint*)B;
    int tid = threadIdx.x, fp = tid & 15, g = tid >> 4;
    v2f bv = (v2f){bias[2 * fp], bias[2 * fp + 1]};
    v2f a1 = (v2f)0.f, a2 = (v2f)0.f;
    for (int n = blockIdx.x * 16 + g; n < N_NODES; n += gridDim.x * 16) {
        int lo = off[n], hi = off[n + 1];
        v2f acc0 = (v2f)0.f, acc1 = (v2f)0.f, acc2 = (v2f)0.f, acc3 = (v2f)0.f;
        int p = lo;
        for (; p + 3 < hi; p += 4) {
            int2 e0 = epk[p], e1 = epk[p + 1], e2 = epk[p + 2], e3 = epk[p + 3];
            float n0 = __int_as_float(e0.y), n1 = __int_as_float(e1.y);
            float n2 = __int_as_float(e2.y), n3 = __int_as_float(e3.y);
            acc0 = vfma(up(Au[(long)e0.x * 16 + fp]), (v2f){n0, n0}, acc0);
            acc1 = vfma(up(Au[(long)e1.x * 16 + fp]), (v2f){n1, n1}, acc1);
            acc2 = vfma(up(Au[(long)e2.x * 16 + fp]), (v2f){n2, n2}, acc2);
            acc3 = vfma(up(Au[(long)e3.x * 16 + fp]), (v2f){n3, n3}, acc3);
        }
        for (; p < hi; p++) {
            int2 e0 = epk[p];
            float n0 = __int_as_float(e0.y);
            acc0 = vfma(up(Au[(long)e0.x * 16 + fp]), (v2f){n0, n0}, acc0);
        }
        float si = frcp(deg[n] + 1.0f);
        v2f v = vfma(up(Au[(long)n * 16 + fp]), (v2f){si, si},
                     (acc0 + acc1) + (acc2 + acc3)) + bv;
        v.x = fmaxf(v.x, 0.f); v.y = fmaxf(v.y, 0.f);
        Bu[(long)n * 16 + fp] = pkv(v);
        a1 += v; a2 += v * v;
    }
    s1[tid] = a1; s2[tid] = a2; __syncthreads();
    for (int st = 128; st >= 16; st >>= 1) {
        if (tid < st) { s1[tid] += s1[tid + st]; s2[tid] += s2[tid + st]; }
        __syncthreads();
    }
    if (tid < 16) {
        atomicAdd(&sum[2 * tid], s1[tid].x); atomicAdd(&sum[2 * tid + 1], s1[tid].y);
        atomicAdd(&sq[2 * tid], s2[tid].x);  atomicAdd(&sq[2 * tid + 1], s2[tid].y);
    }
}

// ---- BN1 finalize ----------------------------------------------------------
__global__ void k_fin1(const float* __restrict__ sum, const float* __restrict__ sq,
                       const float* __restrict__ g, const float* __restrict__ be,
                       float* __restrict__ scale, float* __restrict__ shift) {
    int t = threadIdx.x;
    if (t < 32) {
        float mu = sum[t] / (float)N_NODES;
        float var = sq[t] / (float)N_NODES - mu * mu;
        float rs = rsqrtf(var + BN_EPS) * g[t];
        scale[t] = rs;
        shift[t] = be[t] - mu * rs;
    }
}

// ---- H = affine(B) (bf16); A = H @ W2 (bf16) -------------------------------
__global__ void k_aff_xw(const bf16* __restrict__ B, const float* __restrict__ scale,
                         const float* __restrict__ shift, const float* __restrict__ w,
                         bf16* __restrict__ H, bf16* __restrict__ A) {
    __shared__ float Ws[32 * 33];
    __shared__ float hs[256];
    for (int i = threadIdx.x; i < 1024; i += 256)
        Ws[(i >> 5) * 33 + (i & 31)] = w[i];
    long base = (long)blockIdx.x * 256;
    int f = threadIdx.x & 31;
    float h = b2f(B[base + threadIdx.x]) * scale[f] + shift[f];
    H[base + threadIdx.x] = __float2bfloat16(h);
    hs[threadIdx.x] = h;
    __syncthreads();
    int r = threadIdx.x >> 5, hc = threadIdx.x & 31;
    float acc = 0.f;
#pragma unroll
    for (int k = 0; k < 32; k++) acc += hs[r * 32 + k] * Ws[k * 33 + hc];
    A[base + threadIdx.x] = __float2bfloat16(acc);
}

// ---- BN2 finalize + fc1 const + combined LSTM biases -----------------------
__global__ void k_fin2(const float* __restrict__ sum, const float* __restrict__ sq,
                       const float* __restrict__ g, const float* __restrict__ be,
                       const float* __restrict__ xsum, const float* __restrict__ fw1,
                       const float* __restrict__ fb1,
                       const float* __restrict__ bih1, const float* __restrict__ bhh1,
                       const float* __restrict__ bih2, const float* __restrict__ bhh2,
                       float* __restrict__ scale, float* __restrict__ shift,
                       float* __restrict__ fc1c, float* __restrict__ lb1,
                       float* __restrict__ lb2) {
    int t = threadIdx.x;
    if (t < 32) {
        float mu = sum[t] / (float)N_NODES;
        float var = sq[t] / (float)N_NODES - mu * mu;
        float rs = rsqrtf(var + BN_EPS) * g[t];
        scale[t] = rs;
        shift[t] = be[t] - mu * rs;
        float c = fb1[t];
        for (int f = 0; f < 32; f++)
            c += (xsum[f] / (float)N_NODES) * fw1[t * 96 + 64 + f];
        fc1c[t] = c;
    }
    if (t < 128) {
        lb1[t] = bih1[t] + bhh1[t];
        lb2[t] = bih2[t] + bhh2[t];
    }
}

// ---- per-node dense stack: 2 THREADS PER NODE (half channels each) ---------
// 256-thr blocks, 782 grid -> 3128 waves (3/SIMD, was 1.5). Pair lanes
// (2k,2k+1) share node n; each computes 16 of 32 channels per stage and
// exchanges via __shfl_xor(.,1). bf16-packed LDS weights as in r10.
__global__ __launch_bounds__(256) void k_final(
    const bf16* __restrict__ Hb, const bf16* __restrict__ Bb,
    const float* __restrict__ scale2, const float* __restrict__ shift2,
    const float* __restrict__ wih1, const float* __restrict__ wih2,
    const float* __restrict__ fw1, const float* __restrict__ fw2,
    const float* __restrict__ fb2,
    const float* __restrict__ fc1c, const float* __restrict__ lb1,
    const float* __restrict__ lb2, float* __restrict__ out) {
    __shared__ uint4 Wa4[768];   // LSTM1 bf16x8: i rows 0..255, g 256..511, o 512..767
    __shared__ uint4 Wb4[384];   // LSTM2: i 0..127, g 128..255, o 256..383
    __shared__ uint4 Fc4[256];   // fc1 rows j (k 0..63): j*8+q
    __shared__ float lb1s[128], lb2s[128], fc1s[32], fw2s[32], sc2[32], sh2[32];
    int tid = threadIdx.x;
    for (int i = tid; i < 768; i += 256) {
        int t = i >> 8, rem = i & 255, c = rem >> 3, q = rem & 7;
        int row = (t == 0) ? c : ((t == 1) ? c + 64 : c + 96);
        const float* b = wih1 + row * 64 + q * 8;
        Wa4[i] = make_uint4(pk2(b), pk2(b + 2), pk2(b + 4), pk2(b + 6));
    }
    for (int i = tid; i < 384; i += 256) {
        int t = i >> 7, rem = i & 127, c = rem >> 2, q = rem & 3;
        int row = (t == 0) ? c : ((t == 1) ? c + 64 : c + 96);
        const float* b = wih2 + row * 32 + q * 8;
        Wb4[i] = make_uint4(pk2(b), pk2(b + 2), pk2(b + 4), pk2(b + 6));
    }
    for (int i = tid; i < 256; i += 256) {
        int j = i >> 3, q = i & 7;
        const float* b = fw1 + j * 96 + q * 8;
        Fc4[i] = make_uint4(pk2(b), pk2(b + 2), pk2(b + 4), pk2(b + 6));
    }
    if (tid < 128) { lb1s[tid] = lb1[tid]; lb2s[tid] = lb2[tid]; }
    if (tid >= 128 && tid < 160) {
        int t = tid - 128;
        fc1s[t] = fc1c[t]; fw2s[t] = fw2[t];
        sc2[t] = scale2[t]; sh2[t] = shift2[t];
    }
    __syncthreads();
    int half = tid & 1;
    int n = blockIdx.x * 128 + (tid >> 1);
    if (n >= N_NODES) return;

    v2f cat2[32];
    {
        const uint4* Hv = (const uint4*)((const ushort*)Hb + (long)n * 32);
        const uint4* Bv = (const uint4*)((const ushort*)Bb + (long)n * 32);
#pragma unroll
        for (int q = 0; q < 4; q++) {
            uint4 hu = Hv[q], bu = Bv[q];
            uint hw[4] = {hu.x, hu.y, hu.z, hu.w};
            uint bw[4] = {bu.x, bu.y, bu.z, bu.w};
#pragma unroll
            for (int r = 0; r < 4; r++) {
                int u = q * 4 + r;
                int e0 = 2 * u, e1 = 2 * u + 1;
                cat2[u] = up(hw[r]);
                cat2[16 + u] = vfma(up(bw[r]),
                                    (v2f){sc2[e0], sc2[e1]},
                                    (v2f){sh2[e0], sh2[e1]});
            }
        }
    }
    // ---- LSTM1: my 16 channels, then pair-exchange to full h1 --------------
    float my1[16];
#pragma unroll
    for (int ci = 0; ci < 16; ci++) {
        int c = half * 16 + ci;
        v2f ai = (v2f)0.f, ag = (v2f)0.f, ao = (v2f)0.f;
#pragma unroll
        for (int q = 0; q < 8; q++) {
            uint4 wi = Wa4[c * 8 + q], wg = Wa4[256 + c * 8 + q], wo = Wa4[512 + c * 8 + q];
            uint wiw[4] = {wi.x, wi.y, wi.z, wi.w};
            uint wgw[4] = {wg.x, wg.y, wg.z, wg.w};
            uint wow[4] = {wo.x, wo.y, wo.z, wo.w};
#pragma unroll
            for (int r = 0; r < 4; r++) {
                v2f x0 = cat2[q * 4 + r];
                ai = vfma(up(wiw[r]), x0, ai);
                ag = vfma(up(wgw[r]), x0, ag);
                ao = vfma(up(wow[r]), x0, ao);
            }
        }
        float gi = ai.x + ai.y + lb1s[c];
        float gg = ag.x + ag.y + lb1s[64 + c];
        float go = ao.x + ao.y + lb1s[96 + c];
        float c1 = fsig(gi) * ftanh(gg);
        my1[ci] = fsig(go) * ftanh(c1);
    }
    v2f h1[16];
#pragma unroll
    for (int i = 0; i < 16; i++) {
        float mine = my1[i];
        float other = __shfl_xor(mine, 1);
        h1[i >> 1][i & 1] = half ? other : mine;          // channel i
        h1[8 + (i >> 1)][i & 1] = half ? mine : other;    // channel 16+i
    }
    // ---- LSTM2 -------------------------------------------------------------
    float my2[16];
#pragma unroll
    for (int ci = 0; ci < 16; ci++) {
        int c = half * 16 + ci;
        v2f ai = (v2f)0.f, ag = (v2f)0.f, ao = (v2f)0.f;
#pragma unroll
        for (int q = 0; q < 4; q++) {
            uint4 wi = Wb4[c * 4 + q], wg = Wb4[128 + c * 4 + q], wo = Wb4[256 + c * 4 + q];
            uint wiw[4] = {wi.x, wi.y, wi.z, wi.w};
            uint wgw[4] = {wg.x, wg.y, wg.z, wg.w};
            uint wow[4] = {wo.x, wo.y, wo.z, wo.w};
#pragma unroll
            for (int r = 0; r < 4; r++) {
                v2f x0 = h1[q * 4 + r];
                ai = vfma(up(wiw[r]), x0, ai);
                ag = vfma(up(wgw[r]), x0, ag);
                ao = vfma(up(wow[r]), x0, ao);
            }
        }
        float gi = ai.x + ai.y + lb2s[c];
        float gg = ag.x + ag.y + lb2s[64 + c];
        float go = ao.x + ao.y + lb2s[96 + c];
        float c2 = fsig(gi) * ftanh(gg);
        my2[ci] = fsig(go) * ftanh(c2);
    }
    v2f h2[16];
#pragma unroll
    for (int i = 0; i < 16; i++) {
        float mine = my2[i];
        float other = __shfl_xor(mine, 1);
        h2[i >> 1][i & 1] = half ? other : mine;
        h2[8 + (i >> 1)][i & 1] = half ? mine : other;
    }
    // ---- fc1(relu) @ fc2: my 16 rows, pair-reduce --------------------------
    float acc = 0.f;
#pragma unroll
    for (int ji = 0; ji < 16; ji++) {
        int j = half * 16 + ji;
        v2f z = (v2f)0.f;
#pragma unroll
        for (int q = 0; q < 8; q++) {
            uint4 w = Fc4[j * 8 + q];
            uint ww[4] = {w.x, w.y, w.z, w.w};
#pragma unroll
            for (int r = 0; r < 4; r++) {
                v2f y = (q < 4) ? h1[q * 4 + r] : h2[(q - 4) * 4 + r];
                z = vfma(up(ww[r]), y, z);
            }
        }
        float zz = z.x + z.y + fc1s[j];
        acc += fmaxf(zz, 0.f) * fw2s[j];
    }
    acc += __shfl_xor(acc, 1);
    if (!half) out[n] = acc + fb2[0];
}

extern "C" void kernel_launch(void* const* d_in, const int* in_sizes, int n_in,
                              void* d_out, int out_size, void* d_ws, size_t ws_size,
                              hipStream_t stream) {
    const float* x    = (const float*)d_in[0];
    const int*   ei   = (const int*)d_in[1];
    const float* ew   = (const float*)d_in[2];
    const float* w1   = (const float*)d_in[3];
    const float* b1   = (const float*)d_in[4];
    const float* g1   = (const float*)d_in[5];
    const float* be1  = (const float*)d_in[6];
    const float* w2   = (const float*)d_in[7];
    const float* b2   = (const float*)d_in[8];
    const float* g2   = (const float*)d_in[9];
    const float* be2  = (const float*)d_in[10];
    const float* wih1 = (const float*)d_in[11];
    const float* bih1 = (const float*)d_in[13];
    const float* bhh1 = (const float*)d_in[14];
    const float* wih2 = (const float*)d_in[15];
    const float* bih2 = (const float*)d_in[17];
    const float* bhh2 = (const float*)d_in[18];
    const float* fw1  = (const float*)d_in[19];
    const float* fb1  = (const float*)d_in[20];
    const float* fw2  = (const float*)d_in[21];
    const float* fb2  = (const float*)d_in[22];
    float* out = (float*)d_out;

    // ---- workspace layout (40.5 MB; proven ws >= 41.1 MB from r3/r4) -------
    char* ws = (char*)d_ws;
    float* stats = (float*)ws;                          // 576 floats @ 0
    float* xsum   = stats + 0;
    float* bn1sum = stats + 32;
    float* bn1sq  = stats + 64;
    float* bn2sum = stats + 96;
    float* bn2sq  = stats + 128;
    float* scale1 = stats + 160;
    float* shift1 = stats + 192;
    float* scale2 = stats + 224;
    float* shift2 = stats + 256;
    float* fc1c   = stats + 288;
    float* lb1    = stats + 320;
    float* lb2    = stats + 448;
    ull*   pk    = (ull*)  (ws + 4096);                 // 100000 ull -> 804,096
    int*   bsum  = (int*)  (ws + 804096);               // 391 i
    int*   bbase = (int*)  (ws + 808192);               // 391 i
    int*   off   = (int*)  (ws + 1048576);              // 100001 i -> 1,448,580
    float* deg   = (float*)(ws + 1572864);              // 100000 f -> 1,972,864
    int2*  epk   = (int2*) (ws + 2097152);              // 1.6M int2 -> 14,897,152
    int*   rank  = (int*)  (ws + 14897152);             // 1.6M i -> 21,297,152
    bf16*  A     = (bf16*) (ws + 21297152);             // 6.4MB -> 27,697,152
    bf16*  H     = (bf16*) (ws + 27697152);             // 6.4MB -> 34,097,152
    bf16*  B     = (bf16*) (ws + 34097152);             // 6.4MB -> 40,497,152

    if (ws_size < 40497152ull) {
        k_marker<<<(N_NODES + 255) / 256, 256, 0, stream>>>(out, N_NODES, 911.f);
        return;
    }

    // zero stats + pk in one shot (bytes 0 .. 804,096)
    k_zero_f<<<786, 256, 0, stream>>>(stats, 201024);

    k_hist<<<6250, 256, 0, stream>>>(ei, ew, pk, rank);
    k_bsum<<<SCAN_BLOCKS, 256, 0, stream>>>(pk, bsum);
    k_bscan<<<1, 512, 0, stream>>>(bsum, bbase);
    k_scan3<<<SCAN_BLOCKS, 256, 0, stream>>>(pk, bbase, off, deg);
    k_scatter<<<6250, 256, 0, stream>>>(ei, ew, deg, off, rank, epk);
    k_xmean<<<400, 256, 0, stream>>>(x, xsum);
    k_xw1<<<12500, 256, 0, stream>>>(x, w1, A);
    k_gcn<<<1024, 256, 0, stream>>>(off, epk, A, deg, b1, B, bn1sum, bn1sq);
    k_fin1<<<1, 64, 0, stream>>>(bn1sum, bn1sq, g1, be1, scale1, shift1);
    k_aff_xw<<<12500, 256, 0, stream>>>(B, scale1, shift1, w2, H, A);
    k_gcn<<<1024, 256, 0, stream>>>(off, epk, A, deg, b2, B, bn2sum, bn2sq);
    k_fin2<<<1, 128, 0, stream>>>(bn2sum, bn2sq, g2, be2, xsum, fw1, fb1,
                                  bih1, bhh1, bih2, bhh2,
                                  scale2, shift2, fc1c, lb1, lb2);
    k_final<<<782, 256, 0, stream>>>(H, B, scale2, shift2, wih1, wih2,
                                     fw1, fw2, fb2, fc1c, lb1, lb2, out);
}